// Round 2
// baseline (540.596 us; speedup 1.0000x reference)
//
#include <hip/hip_runtime.h>
#include <hip/hip_bf16.h>
#include <cstdint>

// GraphSAGEMean: x = relu chain of 4 linears over N rows; agg = row-mean of E.
// Fused single-pass kernel: E -> LDS (bf16) -> 4 MFMA layers in-block -> out.
// Weights pre-transposed to [out][in] bf16 in d_ws by prep_kernel (LDS-tiled).
//
// R1 changes: ROWS 128->64 (LDS 67.6->33.8 KB => 4 blocks/CU, 16 waves/CU),
// exact grid (3125*64==200000, no tail checks), coalesced transpose prep.

#define N_ROWS 200000
#define O_DIM  128
#define ROWS   64         // rows per block; 3125 * 64 == 200000 exactly
#define PITCH  264        // 256 + 8 bf16 pad

typedef short bf16x8 __attribute__((ext_vector_type(8)));   // 8 bf16 = 4 VGPRs
typedef float f32x4  __attribute__((ext_vector_type(4)));

__device__ __forceinline__ unsigned short rne_bf16(float f) {
  unsigned int u = __float_as_uint(f);
  u += 0x7FFFu + ((u >> 16) & 1u);      // round-to-nearest-even
  return (unsigned short)(u >> 16);
}

// LDS-tiled transpose + bf16 cast: Wt[o][k] = bf16(W[k][o]).
// ws layout (ushort elems): Wt1 @0, Wt2 @65536, Wt3 @131072, Wto @196608.
// 56 blocks of 64x64 tiles; reads and writes both coalesced.
__global__ __launch_bounds__(256) void prep_kernel(
    const float* __restrict__ W1, const float* __restrict__ W2,
    const float* __restrict__ W3, const float* __restrict__ Wo,
    unsigned short* __restrict__ wt) {
  __shared__ float tile[64][65];
  const int b = blockIdx.x;
  int which, tb;
  if (b < 48) { which = b >> 4; tb = b & 15; }
  else        { which = 3;      tb = b - 48; }
  const float* W = (which == 0) ? W1 : (which == 1) ? W2 : (which == 2) ? W3 : Wo;
  const int O = (which == 3) ? 128 : 256;
  unsigned short* out = wt + (size_t)which * 65536;
  const int otiles = O >> 6;
  const int r0 = (tb / otiles) * 64;    // K-tile origin
  const int c0 = (tb % otiles) * 64;    // O-tile origin

  const int j  = threadIdx.x & 63;
  const int ib = threadIdx.x >> 6;
#pragma unroll
  for (int ii = 0; ii < 16; ++ii) {
    const int i = ii * 4 + ib;
    tile[i][j] = W[(size_t)(r0 + i) * O + c0 + j];   // coalesced read
  }
  __syncthreads();
#pragma unroll
  for (int ii = 0; ii < 16; ++ii) {
    const int i = ii * 4 + ib;
    out[(size_t)(c0 + i) * 256 + r0 + j] = rne_bf16(tile[j][i]);  // coalesced write
  }
}

// One layer, operand-swapped: D[m=out_ch][n=row] = sum_k Wt[m][k] * act[n][k].
// A-frag (Wt) from global (L2-hot), B-frag (act) from LDS, C written back to
// act as bf16 (4 consecutive channels per lane -> 8B LDS write).
template <int MB, bool RELU, bool LAST>
__device__ __forceinline__ void do_layer(
    const unsigned short* __restrict__ wt, const float* __restrict__ bias,
    float* __restrict__ out_x, long row0, unsigned short* act,
    int wave, int lane) {
  const int lc   = lane & 15;
  const int quad = lane >> 4;
  const int m_base = wave * (MB * 16);   // 64 ch/wave (layers 1-3), 32 (layer 4)
  constexpr int NB = ROWS / 16;          // 4 row-blocks of 16

  f32x4 acc[MB][NB];
#pragma unroll
  for (int mb = 0; mb < MB; ++mb)
#pragma unroll
    for (int nb = 0; nb < NB; ++nb)
      acc[mb][nb] = (f32x4){0.f, 0.f, 0.f, 0.f};

#pragma unroll
  for (int k0 = 0; k0 < 256; k0 += 32) {
    bf16x8 bfr[NB];
#pragma unroll
    for (int nb = 0; nb < NB; ++nb)
      bfr[nb] = *(const bf16x8*)&act[(nb * 16 + lc) * PITCH + k0 + 8 * quad];
#pragma unroll
    for (int mb = 0; mb < MB; ++mb) {
      bf16x8 afr = *(const bf16x8*)&wt[(m_base + mb * 16 + lc) * 256 + k0 + 8 * quad];
#pragma unroll
      for (int nb = 0; nb < NB; ++nb)
        acc[mb][nb] = __builtin_amdgcn_mfma_f32_16x16x32_bf16(afr, bfr[nb],
                                                              acc[mb][nb], 0, 0, 0);
    }
  }
  __syncthreads();   // all B-frag reads of act done before overwrite

#pragma unroll
  for (int mb = 0; mb < MB; ++mb) {
    const int ch = m_base + mb * 16 + 4 * quad;
    f32x4 bb = *(const f32x4*)(bias + ch);
#pragma unroll
    for (int nb = 0; nb < NB; ++nb) {
      f32x4 v = acc[mb][nb] + bb;
      if (RELU) {
#pragma unroll
        for (int j = 0; j < 4; ++j) v[j] = fmaxf(v[j], 0.f);
      }
      const int r = nb * 16 + lc;
      if (!LAST) {
        ushort4 h;
        h.x = rne_bf16(v[0]); h.y = rne_bf16(v[1]);
        h.z = rne_bf16(v[2]); h.w = rne_bf16(v[3]);
        *(ushort4*)&act[r * PITCH + ch] = h;          // 8B LDS write
      } else {
        *(f32x4*)&out_x[(row0 + r) * O_DIM + ch] = v;  // 16B store, no tail
      }
    }
  }
  __syncthreads();   // writes visible before next layer's reads
}

__global__ __launch_bounds__(256, 4) void sage_kernel(
    const float* __restrict__ E,
    const float* __restrict__ b1, const float* __restrict__ b2,
    const float* __restrict__ b3, const float* __restrict__ bo,
    const unsigned short* __restrict__ wts,
    float* __restrict__ out_x, float* __restrict__ out_agg) {
  __shared__ __align__(16) unsigned short act[ROWS * PITCH];  // 33792 B -> 4 blk/CU

  const int t    = threadIdx.x;
  const int wave = t >> 6;
  const int lane = t & 63;
  const long row0 = (long)blockIdx.x * ROWS;

  // Load E tile -> bf16 LDS; fused row-mean (output 1).
#pragma unroll
  for (int i = 0; i < ROWS / 4; ++i) {
    const int r = 4 * i + wave;          // wave g handles rows == g (mod 4)
    const long gr = row0 + r;
    f32x4 v = *(const f32x4*)(E + gr * 256 + lane * 4);
    ushort4 h;
    h.x = rne_bf16(v[0]); h.y = rne_bf16(v[1]);
    h.z = rne_bf16(v[2]); h.w = rne_bf16(v[3]);
    *(ushort4*)&act[r * PITCH + lane * 4] = h;
    float s = v[0] + v[1] + v[2] + v[3];
    s += __shfl_down(s, 32);
    s += __shfl_down(s, 16);
    s += __shfl_down(s, 8);
    s += __shfl_down(s, 4);
    s += __shfl_down(s, 2);
    s += __shfl_down(s, 1);
    if (lane == 0) out_agg[gr] = s * (1.0f / 256.0f);
  }
  __syncthreads();

  do_layer<4, true,  false>(wts,          b1, nullptr, row0, act, wave, lane);
  do_layer<4, true,  false>(wts + 65536,  b2, nullptr, row0, act, wave, lane);
  do_layer<4, true,  false>(wts + 131072, b3, nullptr, row0, act, wave, lane);
  do_layer<2, false, true >(wts + 196608, bo, out_x,   row0, act, wave, lane);
}

extern "C" void kernel_launch(void* const* d_in, const int* in_sizes, int n_in,
                              void* d_out, int out_size, void* d_ws, size_t ws_size,
                              hipStream_t stream) {
  const float* E  = (const float*)d_in[0];
  // d_in[1] = adj_keys: mathematically unused (identity gather in reference)
  const float* W1 = (const float*)d_in[2];
  const float* b1 = (const float*)d_in[3];
  const float* W2 = (const float*)d_in[4];
  const float* b2 = (const float*)d_in[5];
  const float* W3 = (const float*)d_in[6];
  const float* b3 = (const float*)d_in[7];
  const float* Wo = (const float*)d_in[8];
  const float* bo = (const float*)d_in[9];

  float* out_x   = (float*)d_out;
  float* out_agg = out_x + (size_t)N_ROWS * O_DIM;
  unsigned short* wts = (unsigned short*)d_ws;   // 458752 B used

  prep_kernel<<<56, 256, 0, stream>>>(W1, W2, W3, Wo, wts);

  const int grid = N_ROWS / ROWS;   // 3125, exact
  sage_kernel<<<grid, 256, 0, stream>>>(E, b1, b2, b3, bo, wts, out_x, out_agg);
}